// Round 1
// baseline (506.263 us; speedup 1.0000x reference)
//
#include <hip/hip_runtime.h>
#include <math.h>

// ---------------------------------------------------------------------------
// GCN forward: 3x GCNConv (sym-norm, self-loops) + linear + global max pool.
// N=50000, E=800000, F=256, H=128, O=64, fp32 throughout.
//
// Strategy:
//   deg/dinv from dst histogram; CSR (by dst) built per-launch (same work
//   every call), reused across the 3 conv layers. GEMM epilogue fuses the
//   dinv row-scale; aggregation is wave-per-dst, atomic-free. Final GEMM
//   fuses +blin and the global max pool via encoded-uint atomicMax.
// ---------------------------------------------------------------------------

__device__ __forceinline__ unsigned enc_f32(float f) {
    unsigned u = __float_as_uint(f);
    return (u & 0x80000000u) ? ~u : (u | 0x80000000u);
}
__device__ __forceinline__ float dec_f32(unsigned e) {
    return (e & 0x80000000u) ? __uint_as_float(e & 0x7fffffffu)
                             : __uint_as_float(~e);
}
#define ENC_NEG_INF 0x007FFFFFu  // enc(-inf)

// ---------------------------------------------------------------- small utils
__global__ void k_init_gmax(unsigned* __restrict__ g) {
    g[threadIdx.x] = ENC_NEG_INF;
}

__global__ void k_count(const int* __restrict__ dst, int* __restrict__ counts, int E) {
    int e = blockIdx.x * blockDim.x + threadIdx.x;
    if (e < E) atomicAdd(&counts[dst[e]], 1);
}

__global__ void k_dinv(const int* __restrict__ counts, float* __restrict__ dinv, int N) {
    int i = blockIdx.x * blockDim.x + threadIdx.x;
    if (i < N) dinv[i] = rsqrtf((float)(counts[i] + 1));  // +1 self-loop; deg>=1 always
}

// -------------------------------------------------------------- 3-pass scan
__global__ __launch_bounds__(1024) void k_scan1(const int* __restrict__ counts,
                                                int* __restrict__ excl,
                                                int* __restrict__ bsums, int N) {
    __shared__ int sh[1024];
    int t = threadIdx.x;
    int i = blockIdx.x * 1024 + t;
    int v = (i < N) ? counts[i] : 0;
    sh[t] = v;
    __syncthreads();
    for (int off = 1; off < 1024; off <<= 1) {
        int tv = (t >= off) ? sh[t - off] : 0;
        __syncthreads();
        sh[t] += tv;
        __syncthreads();
    }
    if (i < N) excl[i] = sh[t] - v;
    if (t == 1023) bsums[blockIdx.x] = sh[1023];
}

__global__ void k_scan2(const int* __restrict__ bsums, int* __restrict__ bofs, int nb) {
    __shared__ int sh[64];
    int t = threadIdx.x;
    int v = (t < nb) ? bsums[t] : 0;
    sh[t] = v;
    __syncthreads();
    for (int off = 1; off < 64; off <<= 1) {
        int tv = (t >= off) ? sh[t - off] : 0;
        __syncthreads();
        sh[t] += tv;
        __syncthreads();
    }
    if (t < nb) bofs[t] = sh[t] - v;
}

__global__ void k_scan3(int* __restrict__ rofs, int* __restrict__ pos,
                        const int* __restrict__ bofs, int N, int E) {
    int i = blockIdx.x * blockDim.x + threadIdx.x;
    if (i < N) {
        int v = rofs[i] + bofs[i >> 10];
        rofs[i] = v;
        pos[i]  = v;
    }
    if (i == 0) rofs[N] = E;
}

__global__ void k_fill(const int* __restrict__ src, const int* __restrict__ dst,
                       int* __restrict__ pos, int* __restrict__ csr, int E) {
    int e = blockIdx.x * blockDim.x + threadIdx.x;
    if (e < E) {
        int p = atomicAdd(&pos[dst[e]], 1);
        csr[p] = src[e];  // order within a dst row irrelevant (sum)
    }
}

// -------------------------------------------------------------------- GEMM
// out[r][c] = dinv[r] * sum_k A[r][k] * W[k][c]
// block: 256 thr, tile 64 rows x M cols, micro-tile 4 x (M/16) per thread.
template <int K, int M>
__global__ __launch_bounds__(256) void k_gemm_scale(const float* __restrict__ A,
                                                    const float* __restrict__ W,
                                                    const float* __restrict__ dinv,
                                                    float* __restrict__ out, int N) {
    constexpr int TR = 64, KB = 32, MC = M / 16, AST = 72;  // AST=72 -> 2-way LDS aliasing (free)
    __shared__ float As[KB][AST];
    __shared__ float Bs[KB][M];
    const int tid = threadIdx.x;
    const int tcol = tid & 15, trow = tid >> 4;
    const int R0 = blockIdx.x * TR;

    float acc[4][MC];
#pragma unroll
    for (int i = 0; i < 4; i++)
#pragma unroll
        for (int j = 0; j < MC; j++) acc[i][j] = 0.f;

    for (int k0 = 0; k0 < K; k0 += KB) {
#pragma unroll
        for (int it = 0; it < 2; ++it) {  // A: 64x32 floats, transposed into LDS
            int l = tid + it * 256;
            int r = l >> 3;
            int kk = (l & 7) << 2;
            float4 g = {0.f, 0.f, 0.f, 0.f};
            if (R0 + r < N) g = *(const float4*)&A[(size_t)(R0 + r) * K + k0 + kk];
            As[kk + 0][r] = g.x;
            As[kk + 1][r] = g.y;
            As[kk + 2][r] = g.z;
            As[kk + 3][r] = g.w;
        }
        constexpr int BIT = (KB * M) / (4 * 256);
#pragma unroll
        for (int it = 0; it < BIT; ++it) {  // B: 32 x M floats, straight copy
            int l = tid + it * 256;
            int kk = l / (M / 4);
            int c4 = (l % (M / 4)) << 2;
            *(float4*)&Bs[kk][c4] = *(const float4*)&W[(size_t)(k0 + kk) * M + c4];
        }
        __syncthreads();
#pragma unroll
        for (int kk = 0; kk < KB; ++kk) {
            float4 af = *(const float4*)&As[kk][trow << 2];
            float a4[4] = {af.x, af.y, af.z, af.w};
            float b[MC];
#pragma unroll
            for (int j = 0; j < MC; j += 4)
                *(float4*)&b[j] = *(const float4*)&Bs[kk][tcol * MC + j];
#pragma unroll
            for (int i = 0; i < 4; i++)
#pragma unroll
                for (int j = 0; j < MC; j++) acc[i][j] = fmaf(a4[i], b[j], acc[i][j]);
        }
        __syncthreads();
    }
#pragma unroll
    for (int i = 0; i < 4; i++) {
        int r = R0 + (trow << 2) + i;
        if (r < N) {
            float s = dinv[r];
#pragma unroll
            for (int j = 0; j < MC; j += 4) {
                float4 o;
                o.x = acc[i][j + 0] * s;
                o.y = acc[i][j + 1] * s;
                o.z = acc[i][j + 2] * s;
                o.w = acc[i][j + 3] * s;
                *(float4*)&out[(size_t)r * M + tcol * MC + j] = o;
            }
        }
    }
}

// ------------------------------------------------ final GEMM + bias + maxpool
// h3[N,128] @ Wlin[128,64] + blin, then global max per column -> gmax (encoded)
__global__ __launch_bounds__(256) void k_gemm_max(const float* __restrict__ A,
                                                  const float* __restrict__ W,
                                                  const float* __restrict__ blin,
                                                  unsigned* __restrict__ gmax, int N) {
    constexpr int K = 128, M = 64, TR = 64, KB = 32, MC = 4, AST = 72;
    __shared__ float As[KB][AST];
    __shared__ float Bs[KB][M];
    __shared__ unsigned smax[M];
    const int tid = threadIdx.x;
    const int tcol = tid & 15, trow = tid >> 4;
    const int R0 = blockIdx.x * TR;

    float acc[4][MC];
#pragma unroll
    for (int i = 0; i < 4; i++)
#pragma unroll
        for (int j = 0; j < MC; j++) acc[i][j] = 0.f;

    for (int k0 = 0; k0 < K; k0 += KB) {
#pragma unroll
        for (int it = 0; it < 2; ++it) {
            int l = tid + it * 256;
            int r = l >> 3;
            int kk = (l & 7) << 2;
            float4 g = {0.f, 0.f, 0.f, 0.f};
            if (R0 + r < N) g = *(const float4*)&A[(size_t)(R0 + r) * K + k0 + kk];
            As[kk + 0][r] = g.x;
            As[kk + 1][r] = g.y;
            As[kk + 2][r] = g.z;
            As[kk + 3][r] = g.w;
        }
#pragma unroll
        for (int it = 0; it < 2; ++it) {
            int l = tid + it * 256;
            int kk = l / (M / 4);
            int c4 = (l % (M / 4)) << 2;
            *(float4*)&Bs[kk][c4] = *(const float4*)&W[(size_t)(k0 + kk) * M + c4];
        }
        __syncthreads();
#pragma unroll
        for (int kk = 0; kk < KB; ++kk) {
            float4 af = *(const float4*)&As[kk][trow << 2];
            float a4[4] = {af.x, af.y, af.z, af.w};
            float b[MC];
            *(float4*)&b[0] = *(const float4*)&Bs[kk][tcol * MC];
#pragma unroll
            for (int i = 0; i < 4; i++)
#pragma unroll
                for (int j = 0; j < MC; j++) acc[i][j] = fmaf(a4[i], b[j], acc[i][j]);
        }
        __syncthreads();
    }
    if (tid < M) smax[tid] = ENC_NEG_INF;
    __syncthreads();
#pragma unroll
    for (int j = 0; j < MC; j++) {
        int c = tcol * MC + j;
        float m = -INFINITY;
        bool any = false;
#pragma unroll
        for (int i = 0; i < 4; i++) {
            int r = R0 + (trow << 2) + i;
            if (r < N) {
                any = true;
                m = fmaxf(m, acc[i][j]);
            }
        }
        if (any) atomicMax(&smax[c], enc_f32(m + blin[c]));
    }
    __syncthreads();
    if (tid < M) atomicMax(&gmax[tid], smax[tid]);
}

__global__ void k_decode(const unsigned* __restrict__ g, float* __restrict__ out) {
    out[threadIdx.x] = dec_f32(g[threadIdx.x]);
}

// ------------------------------------------------------------- aggregation
// out[d][:] = dinv[d] * (sum_{s in CSR[d]} tmp[s][:] + tmp[d][:]) + bias
// one wave per dst node; float2 per lane (128 feats / 64 lanes).
__global__ __launch_bounds__(256) void k_agg(const float* __restrict__ tmp,
                                             const float* __restrict__ dinv,
                                             const int* __restrict__ rofs,
                                             const int* __restrict__ csr,
                                             const float* __restrict__ bias,
                                             float* __restrict__ out, int N) {
    const int lane = threadIdx.x & 63;
    const int d = blockIdx.x * 4 + (threadIdx.x >> 6);
    if (d >= N) return;
    const float2* t2 = (const float2*)tmp;
    const int col = lane;
    int beg = rofs[d], end = rofs[d + 1];
    float2 self = t2[(size_t)d * 64 + col];
    float ax = self.x, ay = self.y;  // self-loop term
    int j = beg;
    for (; j + 4 <= end; j += 4) {
        int s0 = csr[j], s1 = csr[j + 1], s2 = csr[j + 2], s3 = csr[j + 3];
        float2 v0 = t2[(size_t)s0 * 64 + col];
        float2 v1 = t2[(size_t)s1 * 64 + col];
        float2 v2 = t2[(size_t)s2 * 64 + col];
        float2 v3 = t2[(size_t)s3 * 64 + col];
        ax += v0.x + v1.x + v2.x + v3.x;
        ay += v0.y + v1.y + v2.y + v3.y;
    }
    for (; j < end; ++j) {
        int s = csr[j];
        float2 v = t2[(size_t)s * 64 + col];
        ax += v.x;
        ay += v.y;
    }
    float di = dinv[d];
    float2 bv = ((const float2*)bias)[lane];
    float2 o;
    o.x = fmaf(di, ax, bv.x);
    o.y = fmaf(di, ay, bv.y);
    ((float2*)out)[(size_t)d * 64 + col] = o;
}

// ---------------------------------------------------------------------------
extern "C" void kernel_launch(void* const* d_in, const int* in_sizes, int n_in,
                              void* d_out, int out_size, void* d_ws, size_t ws_size,
                              hipStream_t stream) {
    const float* x    = (const float*)d_in[0];
    const int*   ei   = (const int*)d_in[1];  // [2,E]: row0=src, row1=dst
    const float* W0   = (const float*)d_in[3];
    const float* b0   = (const float*)d_in[4];
    const float* W1   = (const float*)d_in[5];
    const float* b1   = (const float*)d_in[6];
    const float* W2   = (const float*)d_in[7];
    const float* b2   = (const float*)d_in[8];
    const float* Wlin = (const float*)d_in[9];
    const float* blin = (const float*)d_in[10];
    float* out = (float*)d_out;

    const int N = in_sizes[2];      // batch vector length = #nodes
    const int E = in_sizes[1] / 2;  // edge_index is [2,E]
    const int* src = ei;
    const int* dst = ei + E;

    // workspace carve (256B aligned)
    size_t off = 0;
    auto carve = [&](size_t bytes) {
        void* p = (char*)d_ws + off;
        off += (bytes + 255) & ~(size_t)255;
        return p;
    };
    int*      counts = (int*)carve((size_t)N * 4);
    int*      pos    = (int*)carve((size_t)N * 4);
    float*    dinv   = (float*)carve((size_t)N * 4);
    int*      rofs   = (int*)carve((size_t)(N + 1) * 4);
    int*      bsums  = (int*)carve(64 * 4);
    int*      bofs   = (int*)carve(64 * 4);
    int*      csr    = (int*)carve((size_t)E * 4);
    float*    tmpA   = (float*)carve((size_t)N * 128 * 4);
    float*    tmpB   = (float*)carve((size_t)N * 128 * 4);
    unsigned* gmax   = (unsigned*)carve(64 * 4);
    (void)ws_size; (void)n_in; (void)out_size;

    const int nbE  = (E + 255) / 256;
    const int nbN  = (N + 255) / 256;
    const int nbS  = (N + 1023) / 1024;      // <=64 required (N<=65536 ok)
    const int nbG  = (N + 63) / 64;          // gemm blocks (64-row tiles)
    const int nbAg = (N + 3) / 4;            // agg blocks (4 dst/block)

    hipMemsetAsync(counts, 0, (size_t)N * 4, stream);
    k_init_gmax<<<1, 64, 0, stream>>>(gmax);

    // graph structure (rebuilt every call; reused across the 3 layers)
    k_count<<<nbE, 256, 0, stream>>>(dst, counts, E);
    k_dinv<<<nbN, 256, 0, stream>>>(counts, dinv, N);
    k_scan1<<<nbS, 1024, 0, stream>>>(counts, rofs, bsums, N);
    k_scan2<<<1, 64, 0, stream>>>(bsums, bofs, nbS);
    k_scan3<<<nbN, 256, 0, stream>>>(rofs, pos, bofs, N, E);
    k_fill<<<nbE, 256, 0, stream>>>(src, dst, pos, csr, E);

    // layer 1: h1 = agg(dinv * (x@W0)) + b0
    k_gemm_scale<256, 128><<<nbG, 256, 0, stream>>>(x, W0, dinv, tmpA, N);
    k_agg<<<nbAg, 256, 0, stream>>>(tmpA, dinv, rofs, csr, b0, tmpB, N);
    // layer 2
    k_gemm_scale<128, 128><<<nbG, 256, 0, stream>>>(tmpB, W1, dinv, tmpA, N);
    k_agg<<<nbAg, 256, 0, stream>>>(tmpA, dinv, rofs, csr, b1, tmpB, N);
    // layer 3
    k_gemm_scale<128, 128><<<nbG, 256, 0, stream>>>(tmpB, W2, dinv, tmpA, N);
    k_agg<<<nbAg, 256, 0, stream>>>(tmpA, dinv, rofs, csr, b2, tmpB, N);
    // linear + global max pool
    k_gemm_max<<<nbG, 256, 0, stream>>>(tmpB, Wlin, blin, gmax, N);
    k_decode<<<1, 64, 0, stream>>>(gmax, out);
}

// Round 2
// 505.084 us; speedup vs baseline: 1.0023x; 1.0023x over previous
//
#include <hip/hip_runtime.h>
#include <math.h>

// ---------------------------------------------------------------------------
// GCN forward: 3x GCNConv (sym-norm, self-loops) + linear + global max pool.
// N=50000, E=800000, F=256, H=128, O=64, fp32 throughout.
//
// R2: GEMM rewritten — 128x128 tile, 8x8 micro-tile, KB=16, conflict-free LDS
// (A-transpose stores hit banks r%32 = 2-way free; b-frag reads split into
// two 64-col-apart float4 so 16 unique addrs are 2-way per bank = free).
// ---------------------------------------------------------------------------

__device__ __forceinline__ unsigned enc_f32(float f) {
    unsigned u = __float_as_uint(f);
    return (u & 0x80000000u) ? ~u : (u | 0x80000000u);
}
__device__ __forceinline__ float dec_f32(unsigned e) {
    return (e & 0x80000000u) ? __uint_as_float(e & 0x7fffffffu)
                             : __uint_as_float(~e);
}
#define ENC_NEG_INF 0x007FFFFFu  // enc(-inf)

// ---------------------------------------------------------------- small utils
__global__ void k_init_gmax(unsigned* __restrict__ g) {
    g[threadIdx.x] = ENC_NEG_INF;
}

__global__ void k_count(const int* __restrict__ dst, int* __restrict__ counts, int E) {
    int e = blockIdx.x * blockDim.x + threadIdx.x;
    if (e < E) atomicAdd(&counts[dst[e]], 1);
}

__global__ void k_dinv(const int* __restrict__ counts, float* __restrict__ dinv, int N) {
    int i = blockIdx.x * blockDim.x + threadIdx.x;
    if (i < N) dinv[i] = rsqrtf((float)(counts[i] + 1));  // +1 self-loop; deg>=1 always
}

// -------------------------------------------------------------- 3-pass scan
__global__ __launch_bounds__(1024) void k_scan1(const int* __restrict__ counts,
                                                int* __restrict__ excl,
                                                int* __restrict__ bsums, int N) {
    __shared__ int sh[1024];
    int t = threadIdx.x;
    int i = blockIdx.x * 1024 + t;
    int v = (i < N) ? counts[i] : 0;
    sh[t] = v;
    __syncthreads();
    for (int off = 1; off < 1024; off <<= 1) {
        int tv = (t >= off) ? sh[t - off] : 0;
        __syncthreads();
        sh[t] += tv;
        __syncthreads();
    }
    if (i < N) excl[i] = sh[t] - v;
    if (t == 1023) bsums[blockIdx.x] = sh[1023];
}

__global__ void k_scan2(const int* __restrict__ bsums, int* __restrict__ bofs, int nb) {
    __shared__ int sh[64];
    int t = threadIdx.x;
    int v = (t < nb) ? bsums[t] : 0;
    sh[t] = v;
    __syncthreads();
    for (int off = 1; off < 64; off <<= 1) {
        int tv = (t >= off) ? sh[t - off] : 0;
        __syncthreads();
        sh[t] += tv;
        __syncthreads();
    }
    if (t < nb) bofs[t] = sh[t] - v;
}

__global__ void k_scan3(int* __restrict__ rofs, int* __restrict__ pos,
                        const int* __restrict__ bofs, int N, int E) {
    int i = blockIdx.x * blockDim.x + threadIdx.x;
    if (i < N) {
        int v = rofs[i] + bofs[i >> 10];
        rofs[i] = v;
        pos[i]  = v;
    }
    if (i == 0) rofs[N] = E;
}

__global__ void k_fill(const int* __restrict__ src, const int* __restrict__ dst,
                       int* __restrict__ pos, int* __restrict__ csr, int E) {
    int e = blockIdx.x * blockDim.x + threadIdx.x;
    if (e < E) {
        int p = atomicAdd(&pos[dst[e]], 1);
        csr[p] = src[e];  // order within a dst row irrelevant (sum)
    }
}

// -------------------------------------------------------------------- GEMM
// EPI=0: out[r][c] = dinv[r] * sum_k A[r][k] * W[k][c]
// EPI=1: gmax[c] = max over r of (sum_k A[r][k]*W[k][c] + blin[c])  (encoded)
// block: 256 thr, tile 128 rows x M cols, micro-tile 8 x (M/16) per thread.
// thread t -> tr = t>>4 (row group, rows tr*8..tr*8+7), tc = t&15.
// thread's cols: chunk f (f < M/64... MC/4) at  f*64 + tc*4 + q, q<4.
template <int K, int M, int EPI>
__global__ __launch_bounds__(256) void k_gemm(const float* __restrict__ A,
                                              const float* __restrict__ W,
                                              const float* __restrict__ sc,   // dinv (EPI=0) or blin (EPI=1)
                                              float* __restrict__ out,        // EPI=0
                                              unsigned* __restrict__ gmax,    // EPI=1
                                              int N) {
    constexpr int TR = 128;      // rows per block
    constexpr int KB = 16;       // k per stage
    constexpr int MC = M / 16;   // cols per thread (8 for M=128, 4 for M=64)
    constexpr int NF = MC / 4;   // float4 col chunks per thread
    __shared__ float As[KB][TR];     // transposed; writes land banks r%32 -> 2-way (free)
    __shared__ float Bs[KB][M];
    __shared__ unsigned smax[64];
    const int tid = threadIdx.x;
    const int tr = tid >> 4;
    const int tc = tid & 15;
    const int R0 = blockIdx.x * TR;

    float acc[8][MC];
#pragma unroll
    for (int i = 0; i < 8; ++i)
#pragma unroll
        for (int j = 0; j < MC; ++j) acc[i][j] = 0.f;

    for (int k0 = 0; k0 < K; k0 += KB) {
        // A tile: 128 rows x 16 k = 512 float4; 2 per thread, transposed store
#pragma unroll
        for (int it = 0; it < 2; ++it) {
            int l = tid + it * 256;
            int r = l & 127;
            int kk = (l >> 7) << 2;  // 0,4,8,12
            float4 g = {0.f, 0.f, 0.f, 0.f};
            if (R0 + r < N) g = *(const float4*)&A[(size_t)(R0 + r) * K + k0 + kk];
            As[kk + 0][r] = g.x;
            As[kk + 1][r] = g.y;
            As[kk + 2][r] = g.z;
            As[kk + 3][r] = g.w;
        }
        // B tile: 16 x M floats
#pragma unroll
        for (int it = 0; it < (KB * M) / (4 * 256); ++it) {
            int l = tid + it * 256;
            int kk = l / (M / 4);
            int c4 = (l % (M / 4)) << 2;
            *(float4*)&Bs[kk][c4] = *(const float4*)&W[(size_t)(k0 + kk) * M + c4];
        }
        __syncthreads();
#pragma unroll
        for (int kk = 0; kk < KB; ++kk) {
            float a[8], b[MC];
            *(float4*)&a[0] = *(const float4*)&As[kk][tr * 8];
            *(float4*)&a[4] = *(const float4*)&As[kk][tr * 8 + 4];
#pragma unroll
            for (int f = 0; f < NF; ++f)
                *(float4*)&b[f * 4] = *(const float4*)&Bs[kk][f * 64 + tc * 4];
#pragma unroll
            for (int i = 0; i < 8; ++i)
#pragma unroll
                for (int j = 0; j < MC; ++j) acc[i][j] = fmaf(a[i], b[j], acc[i][j]);
        }
        __syncthreads();
    }

    if (EPI == 0) {
#pragma unroll
        for (int i = 0; i < 8; ++i) {
            int r = R0 + tr * 8 + i;
            if (r < N) {
                float s = sc[r];
#pragma unroll
                for (int f = 0; f < NF; ++f) {
                    float4 o;
                    o.x = acc[i][f * 4 + 0] * s;
                    o.y = acc[i][f * 4 + 1] * s;
                    o.z = acc[i][f * 4 + 2] * s;
                    o.w = acc[i][f * 4 + 3] * s;
                    *(float4*)&out[(size_t)r * M + f * 64 + tc * 4] = o;
                }
            }
        }
    } else {
        if (tid < 64) smax[tid] = ENC_NEG_INF;
        __syncthreads();
#pragma unroll
        for (int q = 0; q < MC; ++q) {
            float m = -INFINITY;
            bool any = false;
#pragma unroll
            for (int i = 0; i < 8; ++i) {
                if (R0 + tr * 8 + i < N) {
                    any = true;
                    m = fmaxf(m, acc[i][q]);
                }
            }
            int c = tc * 4 + (q & 3) + (q >> 2) * 64;
            if (any) atomicMax(&smax[c], enc_f32(m + sc[c]));
        }
        __syncthreads();
        if (tid < 64) atomicMax(&gmax[tid], smax[tid]);
    }
}

__global__ void k_decode(const unsigned* __restrict__ g, float* __restrict__ out) {
    out[threadIdx.x] = dec_f32(g[threadIdx.x]);
}

// ------------------------------------------------------------- aggregation
// out[d][:] = dinv[d] * (sum_{s in CSR[d]} tmp[s][:] + tmp[d][:]) + bias
// one wave per dst node; float2 per lane (128 feats / 64 lanes).
__global__ __launch_bounds__(256) void k_agg(const float* __restrict__ tmp,
                                             const float* __restrict__ dinv,
                                             const int* __restrict__ rofs,
                                             const int* __restrict__ csr,
                                             const float* __restrict__ bias,
                                             float* __restrict__ out, int N) {
    const int lane = threadIdx.x & 63;
    const int d = blockIdx.x * 4 + (threadIdx.x >> 6);
    if (d >= N) return;
    const float2* t2 = (const float2*)tmp;
    const int col = lane;
    int beg = rofs[d], end = rofs[d + 1];
    float2 self = t2[(size_t)d * 64 + col];
    float ax = self.x, ay = self.y;  // self-loop term
    int j = beg;
    for (; j + 4 <= end; j += 4) {
        int s0 = csr[j], s1 = csr[j + 1], s2 = csr[j + 2], s3 = csr[j + 3];
        float2 v0 = t2[(size_t)s0 * 64 + col];
        float2 v1 = t2[(size_t)s1 * 64 + col];
        float2 v2 = t2[(size_t)s2 * 64 + col];
        float2 v3 = t2[(size_t)s3 * 64 + col];
        ax += v0.x + v1.x + v2.x + v3.x;
        ay += v0.y + v1.y + v2.y + v3.y;
    }
    for (; j < end; ++j) {
        int s = csr[j];
        float2 v = t2[(size_t)s * 64 + col];
        ax += v.x;
        ay += v.y;
    }
    float di = dinv[d];
    float2 bv = ((const float2*)bias)[lane];
    float2 o;
    o.x = fmaf(di, ax, bv.x);
    o.y = fmaf(di, ay, bv.y);
    ((float2*)out)[(size_t)d * 64 + col] = o;
}

// ---------------------------------------------------------------------------
extern "C" void kernel_launch(void* const* d_in, const int* in_sizes, int n_in,
                              void* d_out, int out_size, void* d_ws, size_t ws_size,
                              hipStream_t stream) {
    const float* x    = (const float*)d_in[0];
    const int*   ei   = (const int*)d_in[1];  // [2,E]: row0=src, row1=dst
    const float* W0   = (const float*)d_in[3];
    const float* b0   = (const float*)d_in[4];
    const float* W1   = (const float*)d_in[5];
    const float* b1   = (const float*)d_in[6];
    const float* W2   = (const float*)d_in[7];
    const float* b2   = (const float*)d_in[8];
    const float* Wlin = (const float*)d_in[9];
    const float* blin = (const float*)d_in[10];
    float* out = (float*)d_out;

    const int N = in_sizes[2];      // batch vector length = #nodes
    const int E = in_sizes[1] / 2;  // edge_index is [2,E]
    const int* src = ei;
    const int* dst = ei + E;

    // workspace carve (256B aligned)
    size_t off = 0;
    auto carve = [&](size_t bytes) {
        void* p = (char*)d_ws + off;
        off += (bytes + 255) & ~(size_t)255;
        return p;
    };
    int*      counts = (int*)carve((size_t)N * 4);
    int*      pos    = (int*)carve((size_t)N * 4);
    float*    dinv   = (float*)carve((size_t)N * 4);
    int*      rofs   = (int*)carve((size_t)(N + 1) * 4);
    int*      bsums  = (int*)carve(64 * 4);
    int*      bofs   = (int*)carve(64 * 4);
    int*      csr    = (int*)carve((size_t)E * 4);
    float*    tmpA   = (float*)carve((size_t)N * 128 * 4);
    float*    tmpB   = (float*)carve((size_t)N * 128 * 4);
    unsigned* gmax   = (unsigned*)carve(64 * 4);
    (void)ws_size; (void)n_in; (void)out_size;

    const int nbE  = (E + 255) / 256;
    const int nbN  = (N + 255) / 256;
    const int nbS  = (N + 1023) / 1024;      // <=64 required (N<=65536 ok)
    const int nbG  = (N + 127) / 128;        // gemm blocks (128-row tiles)
    const int nbAg = (N + 3) / 4;            // agg blocks (4 dst/block)

    hipMemsetAsync(counts, 0, (size_t)N * 4, stream);
    k_init_gmax<<<1, 64, 0, stream>>>(gmax);

    // graph structure (rebuilt every call; reused across the 3 layers)
    k_count<<<nbE, 256, 0, stream>>>(dst, counts, E);
    k_dinv<<<nbN, 256, 0, stream>>>(counts, dinv, N);
    k_scan1<<<nbS, 1024, 0, stream>>>(counts, rofs, bsums, N);
    k_scan2<<<1, 64, 0, stream>>>(bsums, bofs, nbS);
    k_scan3<<<nbN, 256, 0, stream>>>(rofs, pos, bofs, N, E);
    k_fill<<<nbE, 256, 0, stream>>>(src, dst, pos, csr, E);

    // layer 1: h1 = agg(dinv * (x@W0)) + b0
    k_gemm<256, 128, 0><<<nbG, 256, 0, stream>>>(x, W0, dinv, tmpA, nullptr, N);
    k_agg<<<nbAg, 256, 0, stream>>>(tmpA, dinv, rofs, csr, b0, tmpB, N);
    // layer 2
    k_gemm<128, 128, 0><<<nbG, 256, 0, stream>>>(tmpB, W1, dinv, tmpA, nullptr, N);
    k_agg<<<nbAg, 256, 0, stream>>>(tmpA, dinv, rofs, csr, b1, tmpB, N);
    // layer 3
    k_gemm<128, 128, 0><<<nbG, 256, 0, stream>>>(tmpB, W2, dinv, tmpA, nullptr, N);
    k_agg<<<nbAg, 256, 0, stream>>>(tmpA, dinv, rofs, csr, b2, tmpB, N);
    // linear + global max pool
    k_gemm<128, 64, 1><<<nbG, 256, 0, stream>>>(tmpB, Wlin, blin, nullptr, gmax, N);
    k_decode<<<1, 64, 0, stream>>>(gmax, out);
}

// Round 3
// 460.763 us; speedup vs baseline: 1.0988x; 1.0962x over previous
//
#include <hip/hip_runtime.h>
#include <math.h>

// ---------------------------------------------------------------------------
// GCN forward: 3x GCNConv (sym-norm, self-loops) + linear + global max pool.
// N=50000, E=800000, F=256, H=128, O=64, fp32 in/out.
//
// R3: GEMMs use split-fp16 MFMA (a = hi + lo, 3 passes hi*hi + hi*lo + lo*hi,
// ~2^-22 per-term error ≈ fp32). Weights pre-packed into MFMA frag order.
// A split fp32->f16hi/lo during LDS staging. Wave tile 64x64, frag reads are
// lane-contiguous ds_read_b128 (conflict-free).
// ---------------------------------------------------------------------------

typedef __attribute__((ext_vector_type(8))) _Float16 f16x8;
typedef __attribute__((ext_vector_type(4))) float f32x4;

__device__ __forceinline__ void split_f16(float a, unsigned short& h, unsigned short& l) {
    _Float16 ah = (_Float16)a;          // RNE
    float r = a - (float)ah;            // exact (Sterbenz)
    _Float16 al = (_Float16)r;          // RNE
    h = __builtin_bit_cast(unsigned short, ah);
    l = __builtin_bit_cast(unsigned short, al);
}

__device__ __forceinline__ unsigned enc_f32(float f) {
    unsigned u = __float_as_uint(f);
    return (u & 0x80000000u) ? ~u : (u | 0x80000000u);
}
__device__ __forceinline__ float dec_f32(unsigned e) {
    return (e & 0x80000000u) ? __uint_as_float(e & 0x7fffffffu)
                             : __uint_as_float(~e);
}
#define ENC_NEG_INF 0x007FFFFFu  // enc(-inf)

// ---------------------------------------------------------------- small utils
__global__ void k_init_gmax(unsigned* __restrict__ g) {
    g[threadIdx.x] = ENC_NEG_INF;
}

__global__ void k_count(const int* __restrict__ dst, int* __restrict__ counts, int E) {
    int e = blockIdx.x * blockDim.x + threadIdx.x;
    if (e < E) atomicAdd(&counts[dst[e]], 1);
}

__global__ void k_dinv(const int* __restrict__ counts, float* __restrict__ dinv, int N) {
    int i = blockIdx.x * blockDim.x + threadIdx.x;
    if (i < N) dinv[i] = rsqrtf((float)(counts[i] + 1));  // +1 self-loop
}

// -------------------------------------------------------------- 3-pass scan
__global__ __launch_bounds__(1024) void k_scan1(const int* __restrict__ counts,
                                                int* __restrict__ excl,
                                                int* __restrict__ bsums, int N) {
    __shared__ int sh[1024];
    int t = threadIdx.x;
    int i = blockIdx.x * 1024 + t;
    int v = (i < N) ? counts[i] : 0;
    sh[t] = v;
    __syncthreads();
    for (int off = 1; off < 1024; off <<= 1) {
        int tv = (t >= off) ? sh[t - off] : 0;
        __syncthreads();
        sh[t] += tv;
        __syncthreads();
    }
    if (i < N) excl[i] = sh[t] - v;
    if (t == 1023) bsums[blockIdx.x] = sh[1023];
}

__global__ void k_scan2(const int* __restrict__ bsums, int* __restrict__ bofs, int nb) {
    __shared__ int sh[64];
    int t = threadIdx.x;
    int v = (t < nb) ? bsums[t] : 0;
    sh[t] = v;
    __syncthreads();
    for (int off = 1; off < 64; off <<= 1) {
        int tv = (t >= off) ? sh[t - off] : 0;
        __syncthreads();
        sh[t] += tv;
        __syncthreads();
    }
    if (t < nb) bofs[t] = sh[t] - v;
}

__global__ void k_scan3(int* __restrict__ rofs, int* __restrict__ pos,
                        const int* __restrict__ bofs, int N, int E) {
    int i = blockIdx.x * blockDim.x + threadIdx.x;
    if (i < N) {
        int v = rofs[i] + bofs[i >> 10];
        rofs[i] = v;
        pos[i]  = v;
    }
    if (i == 0) rofs[N] = E;
}

__global__ void k_fill(const int* __restrict__ src, const int* __restrict__ dst,
                       int* __restrict__ pos, int* __restrict__ csr, int E) {
    int e = blockIdx.x * blockDim.x + threadIdx.x;
    if (e < E) {
        int p = atomicAdd(&pos[dst[e]], 1);
        csr[p] = src[e];
    }
}

// ------------------------------------------------------------ weight packing
// W[K][M] fp32 -> hi/lo f16 planes in MFMA B-frag order:
// flat = ((c*(K/32)+q)*64 + lane)*8 + j ; element = W[q*32+(lane>>4)*8+j][c*16+(lane&15)]
template <int K, int M>
__global__ void k_packw(const float* __restrict__ W, unsigned short* __restrict__ Wh,
                        unsigned short* __restrict__ Wl) {
    int c = blockIdx.x % (M / 16);
    int q = blockIdx.x / (M / 16);
    int l = threadIdx.x;  // 64
    int n = c * 16 + (l & 15);
    int k0 = q * 32 + (l >> 4) * 8;
    size_t base = ((size_t)(c * (K / 32) + q) * 64 + l) * 8;
#pragma unroll
    for (int j = 0; j < 8; ++j) {
        unsigned short h, lo;
        split_f16(W[(size_t)(k0 + j) * M + n], h, lo);
        Wh[base + j] = h;
        Wl[base + j] = lo;
    }
}

// -------------------------------------------------------------------- GEMM
// 128-row block tile, 4 waves in 2x2, wave tile 64 x (M/2).
// EPI=0: out[r][c] = sc[r] * sum_k A[r][k]*W[k][c]
// EPI=1: gmax[c] max= (sum_k A[r][k]*W[k][c] + sc[c])   (encoded atomicMax)
template <int K, int M, int EPI>
__global__ __launch_bounds__(256, 2) void k_gemm(const float* __restrict__ A,
                                                 const unsigned short* __restrict__ Wh,
                                                 const unsigned short* __restrict__ Wl,
                                                 const float* __restrict__ sc,
                                                 float* __restrict__ out,
                                                 unsigned* __restrict__ gmax,
                                                 int N) {
    constexpr int CT = M / 32;  // col-tiles per wave
    constexpr int QK = K / 32;  // k chunks
    __shared__ unsigned short Ah[128 * 32], Al[128 * 32];  // frag order [tile][lane][j]
    __shared__ unsigned short Bh[M * 32], Bl[M * 32];
    __shared__ unsigned smax[64];
    const int tid = threadIdx.x;
    const int lane = tid & 63;
    const int wave = tid >> 6;
    const int wrow = wave >> 1;
    const int wcol = wave & 1;
    const int R0 = blockIdx.x * 128;

    f32x4 acc[4][CT];
#pragma unroll
    for (int rt = 0; rt < 4; ++rt)
#pragma unroll
        for (int ct = 0; ct < CT; ++ct) acc[rt][ct] = (f32x4){0.f, 0.f, 0.f, 0.f};

    for (int q = 0; q < QK; ++q) {
        const int k0 = q * 32;
        // ---- stage A: fp32 load (coalesced), split, frag-order LDS store ----
#pragma unroll
        for (int it = 0; it < 4; ++it) {
            int idx = tid + it * 256;  // 0..1023
            int r = idx >> 3;
            int kk = (idx & 7) << 2;   // 0,4,...,28
            float4 g = {0.f, 0.f, 0.f, 0.f};
            if (R0 + r < N) g = *(const float4*)&A[(size_t)(R0 + r) * K + k0 + kk];
            unsigned short h0, h1, h2, h3, l0, l1, l2, l3;
            split_f16(g.x, h0, l0);
            split_f16(g.y, h1, l1);
            split_f16(g.z, h2, l2);
            split_f16(g.w, h3, l3);
            int fo = ((r >> 4) << 9) + ((((kk >> 3) << 4) | (r & 15)) << 3) + (kk & 7);
            uint2 uh, ul;
            uh.x = (unsigned)h0 | ((unsigned)h1 << 16);
            uh.y = (unsigned)h2 | ((unsigned)h3 << 16);
            ul.x = (unsigned)l0 | ((unsigned)l1 << 16);
            ul.y = (unsigned)l2 | ((unsigned)l3 << 16);
            *(uint2*)&Ah[fo] = uh;
            *(uint2*)&Al[fo] = ul;
        }
        // ---- stage B: pre-packed, straight 16B copies ----
#pragma unroll
        for (int it = 0; it < M / 64; ++it) {
            int idx = tid + it * 256;
            int c = idx >> 6;
            int l = idx & 63;
            size_t gflat = ((size_t)(c * QK + q) * 64 + l) * 8;
            int lflat = (c * 64 + l) * 8;
            *(uint4*)&Bh[lflat] = *(const uint4*)&Wh[gflat];
            *(uint4*)&Bl[lflat] = *(const uint4*)&Wl[gflat];
        }
        __syncthreads();
        // ---- frags + 3-pass mfma ----
        f16x8 ahf[4], alf[4], bhf[CT], blf[CT];
#pragma unroll
        for (int rt = 0; rt < 4; ++rt) {
            int t = wrow * 4 + rt;
            ahf[rt] = *(const f16x8*)&Ah[(t * 64 + lane) * 8];
            alf[rt] = *(const f16x8*)&Al[(t * 64 + lane) * 8];
        }
#pragma unroll
        for (int ct = 0; ct < CT; ++ct) {
            int t = wcol * CT + ct;
            bhf[ct] = *(const f16x8*)&Bh[(t * 64 + lane) * 8];
            blf[ct] = *(const f16x8*)&Bl[(t * 64 + lane) * 8];
        }
#pragma unroll
        for (int rt = 0; rt < 4; ++rt)
#pragma unroll
            for (int ct = 0; ct < CT; ++ct) {
                acc[rt][ct] = __builtin_amdgcn_mfma_f32_16x16x32_f16(ahf[rt], bhf[ct], acc[rt][ct], 0, 0, 0);
                acc[rt][ct] = __builtin_amdgcn_mfma_f32_16x16x32_f16(ahf[rt], blf[ct], acc[rt][ct], 0, 0, 0);
                acc[rt][ct] = __builtin_amdgcn_mfma_f32_16x16x32_f16(alf[rt], bhf[ct], acc[rt][ct], 0, 0, 0);
            }
        __syncthreads();
    }

    const int quad = lane >> 4;
    if (EPI == 0) {
#pragma unroll
        for (int rt = 0; rt < 4; ++rt)
#pragma unroll
            for (int reg = 0; reg < 4; ++reg) {
                int r = R0 + wrow * 64 + rt * 16 + quad * 4 + reg;
                if (r < N) {
                    float s = sc[r];
#pragma unroll
                    for (int ct = 0; ct < CT; ++ct) {
                        int c = wcol * (CT * 16) + ct * 16 + (lane & 15);
                        out[(size_t)r * M + c] = acc[rt][ct][reg] * s;
                    }
                }
            }
    } else {
        if (tid < 64) smax[tid] = ENC_NEG_INF;
        __syncthreads();
        float cm[CT];
#pragma unroll
        for (int ct = 0; ct < CT; ++ct) cm[ct] = -INFINITY;
#pragma unroll
        for (int rt = 0; rt < 4; ++rt)
#pragma unroll
            for (int reg = 0; reg < 4; ++reg) {
                int r = R0 + wrow * 64 + rt * 16 + quad * 4 + reg;
                if (r < N) {
#pragma unroll
                    for (int ct = 0; ct < CT; ++ct) cm[ct] = fmaxf(cm[ct], acc[rt][ct][reg]);
                }
            }
#pragma unroll
        for (int ct = 0; ct < CT; ++ct) {
            float v = cm[ct];
            v = fmaxf(v, __shfl_xor(v, 16, 64));
            v = fmaxf(v, __shfl_xor(v, 32, 64));
            if (lane < 16) {
                int c = wcol * (CT * 16) + ct * 16 + lane;
                atomicMax(&smax[c], enc_f32(v + sc[c]));
            }
        }
        __syncthreads();
        if (tid < 64) atomicMax(&gmax[tid], smax[tid]);
    }
}

__global__ void k_decode(const unsigned* __restrict__ g, float* __restrict__ out) {
    out[threadIdx.x] = dec_f32(g[threadIdx.x]);
}

// ------------------------------------------------------------- aggregation
__global__ __launch_bounds__(256) void k_agg(const float* __restrict__ tmp,
                                             const float* __restrict__ dinv,
                                             const int* __restrict__ rofs,
                                             const int* __restrict__ csr,
                                             const float* __restrict__ bias,
                                             float* __restrict__ out, int N) {
    const int lane = threadIdx.x & 63;
    const int d = blockIdx.x * 4 + (threadIdx.x >> 6);
    if (d >= N) return;
    const float2* t2 = (const float2*)tmp;
    const int col = lane;
    int beg = rofs[d], end = rofs[d + 1];
    float2 self = t2[(size_t)d * 64 + col];
    float ax = self.x, ay = self.y;  // self-loop term
    int j = beg;
    for (; j + 4 <= end; j += 4) {
        int s0 = csr[j], s1 = csr[j + 1], s2 = csr[j + 2], s3 = csr[j + 3];
        float2 v0 = t2[(size_t)s0 * 64 + col];
        float2 v1 = t2[(size_t)s1 * 64 + col];
        float2 v2 = t2[(size_t)s2 * 64 + col];
        float2 v3 = t2[(size_t)s3 * 64 + col];
        ax += v0.x + v1.x + v2.x + v3.x;
        ay += v0.y + v1.y + v2.y + v3.y;
    }
    for (; j < end; ++j) {
        int s = csr[j];
        float2 v = t2[(size_t)s * 64 + col];
        ax += v.x;
        ay += v.y;
    }
    float di = dinv[d];
    float2 bv = ((const float2*)bias)[lane];
    float2 o;
    o.x = fmaf(di, ax, bv.x);
    o.y = fmaf(di, ay, bv.y);
    ((float2*)out)[(size_t)d * 64 + col] = o;
}

// ---------------------------------------------------------------------------
extern "C" void kernel_launch(void* const* d_in, const int* in_sizes, int n_in,
                              void* d_out, int out_size, void* d_ws, size_t ws_size,
                              hipStream_t stream) {
    const float* x    = (const float*)d_in[0];
    const int*   ei   = (const int*)d_in[1];  // [2,E]: row0=src, row1=dst
    const float* W0   = (const float*)d_in[3];
    const float* b0   = (const float*)d_in[4];
    const float* W1   = (const float*)d_in[5];
    const float* b1   = (const float*)d_in[6];
    const float* W2   = (const float*)d_in[7];
    const float* b2   = (const float*)d_in[8];
    const float* Wlin = (const float*)d_in[9];
    const float* blin = (const float*)d_in[10];
    float* out = (float*)d_out;

    const int N = in_sizes[2];
    const int E = in_sizes[1] / 2;
    const int* src = ei;
    const int* dst = ei + E;

    size_t off = 0;
    auto carve = [&](size_t bytes) {
        void* p = (char*)d_ws + off;
        off += (bytes + 255) & ~(size_t)255;
        return p;
    };
    int*      counts = (int*)carve((size_t)N * 4);
    int*      pos    = (int*)carve((size_t)N * 4);
    float*    dinv   = (float*)carve((size_t)N * 4);
    int*      rofs   = (int*)carve((size_t)(N + 1) * 4);
    int*      bsums  = (int*)carve(64 * 4);
    int*      bofs   = (int*)carve(64 * 4);
    int*      csr    = (int*)carve((size_t)E * 4);
    float*    tmpA   = (float*)carve((size_t)N * 128 * 4);
    float*    tmpB   = (float*)carve((size_t)N * 128 * 4);
    unsigned* gmax   = (unsigned*)carve(64 * 4);
    unsigned short* w0h = (unsigned short*)carve(256 * 128 * 2);
    unsigned short* w0l = (unsigned short*)carve(256 * 128 * 2);
    unsigned short* w1h = (unsigned short*)carve(128 * 128 * 2);
    unsigned short* w1l = (unsigned short*)carve(128 * 128 * 2);
    unsigned short* w2h = (unsigned short*)carve(128 * 128 * 2);
    unsigned short* w2l = (unsigned short*)carve(128 * 128 * 2);
    unsigned short* wlh = (unsigned short*)carve(128 * 64 * 2);
    unsigned short* wll = (unsigned short*)carve(128 * 64 * 2);
    (void)ws_size; (void)n_in; (void)out_size;

    const int nbE  = (E + 255) / 256;
    const int nbN  = (N + 255) / 256;
    const int nbS  = (N + 1023) / 1024;
    const int nbG  = (N + 127) / 128;
    const int nbAg = (N + 3) / 4;

    hipMemsetAsync(counts, 0, (size_t)N * 4, stream);
    k_init_gmax<<<1, 64, 0, stream>>>(gmax);

    // weight packing (tiny)
    k_packw<256, 128><<<(128 / 16) * (256 / 32), 64, 0, stream>>>(W0, w0h, w0l);
    k_packw<128, 128><<<(128 / 16) * (128 / 32), 64, 0, stream>>>(W1, w1h, w1l);
    k_packw<128, 128><<<(128 / 16) * (128 / 32), 64, 0, stream>>>(W2, w2h, w2l);
    k_packw<128, 64><<<(64 / 16) * (128 / 32), 64, 0, stream>>>(Wlin, wlh, wll);

    // graph structure
    k_count<<<nbE, 256, 0, stream>>>(dst, counts, E);
    k_dinv<<<nbN, 256, 0, stream>>>(counts, dinv, N);
    k_scan1<<<nbS, 1024, 0, stream>>>(counts, rofs, bsums, N);
    k_scan2<<<1, 64, 0, stream>>>(bsums, bofs, nbS);
    k_scan3<<<nbN, 256, 0, stream>>>(rofs, pos, bofs, N, E);
    k_fill<<<nbE, 256, 0, stream>>>(src, dst, pos, csr, E);

    // layer 1
    k_gemm<256, 128, 0><<<nbG, 256, 0, stream>>>(x, w0h, w0l, dinv, tmpA, nullptr, N);
    k_agg<<<nbAg, 256, 0, stream>>>(tmpA, dinv, rofs, csr, b0, tmpB, N);
    // layer 2
    k_gemm<128, 128, 0><<<nbG, 256, 0, stream>>>(tmpB, w1h, w1l, dinv, tmpA, nullptr, N);
    k_agg<<<nbAg, 256, 0, stream>>>(tmpA, dinv, rofs, csr, b1, tmpB, N);
    // layer 3
    k_gemm<128, 128, 0><<<nbG, 256, 0, stream>>>(tmpB, w2h, w2l, dinv, tmpA, nullptr, N);
    k_agg<<<nbAg, 256, 0, stream>>>(tmpA, dinv, rofs, csr, b2, tmpB, N);
    // linear + global max pool
    k_gemm<128, 64, 1><<<nbG, 256, 0, stream>>>(tmpB, wlh, wll, blin, nullptr, gmax, N);
    k_decode<<<1, 64, 0, stream>>>(gmax, out);
}